// Round 9
// baseline (202.715 us; speedup 1.0000x reference)
//
#include <hip/hip_runtime.h>
#include <hip/hip_bf16.h>
#include <stdint.h>

typedef __attribute__((ext_vector_type(4))) float f32x4;
typedef __attribute__((ext_vector_type(16))) float f32x16;
typedef __attribute__((ext_vector_type(8))) short short8;

#define DEV __device__ __forceinline__

DEV unsigned short f2bf(float f){
  unsigned u = __float_as_uint(f);
  u += 0x7FFFu + ((u >> 16) & 1u);
  return (unsigned short)(u >> 16);
}
// branch-free erf, Abramowitz-Stegun 7.1.26, |err| <= 1.5e-7
DEV float erf_fast(float x){
  float ax = fabsf(x);
  float t = 1.0f / (1.0f + 0.3275911f * ax);
  float p = t * (0.254829592f + t * (-0.284496736f + t * (1.421413741f +
            t * (-1.453152027f + t * 1.061405429f))));
  float r = 1.0f - p * __expf(-ax * ax);
  return copysignf(r, x);
}
DEV float gelu_exact(float x){ return 0.5f * x * (1.0f + erf_fast(x * 0.70710678118654752f)); }

DEV void gl_lds16(const void* g, void* l){
  __builtin_amdgcn_global_load_lds((const __attribute__((address_space(1))) unsigned int*)g,
                                   (__attribute__((address_space(3))) unsigned int*)l, 16, 0, 0);
}

// scale folded into Q: sqrt(1/1024) * log2(e)  -> softmax in exp2 units
#define QSCALE 0.04508422f

// ---------------- conversion fp32 -> bf16 ----------------
struct ConvArgs { const float* src[7]; unsigned short* dst[7]; int n[7]; };

__global__ __launch_bounds__(256) void conv_kernel(ConvArgs a){
  int t = blockIdx.y;
  int i = (blockIdx.x * 256 + threadIdx.x) * 4;
  if (i >= a.n[t]) return;
  float4 v = *(const float4*)(a.src[t] + i);
  ushort4 o;
  o.x = f2bf(v.x); o.y = f2bf(v.y); o.z = f2bf(v.z); o.w = f2bf(v.w);
  *(ushort4*)(a.dst[t] + i) = o;
}

// ---------------- rope table: cos/sin [2048][32] ----------------
__global__ __launch_bounds__(256) void rope_kernel(float2* tab){
  int g = blockIdx.x * 256 + threadIdx.x;
  if (g >= 2048 * 32) return;
  int s = g >> 5, j = g & 31;
  float theta = (float)exp(-(double)j * (9.210340371976184 / 32.0)); // 10000^(-j/32)
  double ang = (double)s * (double)theta;
  tab[g] = make_float2((float)cos(ang), (float)sin(ang));
}

// ============ 128x128 tile GEMM core: BK=64, SINGLE 32KB buffer, 4 waves ============
DEV void gemm_core128(const unsigned short* __restrict__ A, const unsigned short* __restrict__ W,
                      int m0, int n0, char* lds_raw, f32x4 (&acc)[4][4],
                      int lane, int wid, int wr, int wc)
{
  const int srow = wid * 8 + (lane >> 3);          // staging row within 32-row group
  const int scc  = ((lane & 7) ^ (lane >> 3)) * 8; // inverse-swizzled source column (shorts)
  const int rxor = lane & 7;                       // read-side swizzle (chunks)

  for (int kt = 0; kt < 16; ++kt){
    int kk = kt * 64;
    __syncthreads();   // prior compute done -> safe to overwrite LDS
#pragma unroll
    for (int t = 0; t < 4; t++){
      gl_lds16(A + (size_t)(m0 + t * 32 + srow) * 1024 + kk + scc,
               lds_raw + (t * 2048 + wid * 512) * 2);
      gl_lds16(W + (size_t)(n0 + t * 32 + srow) * 1024 + kk + scc,
               lds_raw + 16384 + (t * 2048 + wid * 512) * 2);
    }
    __syncthreads();   // vmcnt drained -> LDS valid
    const unsigned short* Als = (const unsigned short*)lds_raw;
    const unsigned short* Bls = Als + 8192;
#pragma unroll
    for (int dk = 0; dk < 2; ++dk){
      short8 af[4], bfr[4];
      int cidx = (((dk * 4 + (lane >> 4)) ^ rxor) << 3);
#pragma unroll
      for (int i = 0; i < 4; i++){
        af[i]  = *(const short8*)(Als + (wr * 64 + i * 16 + (lane & 15)) * 64 + cidx);
        bfr[i] = *(const short8*)(Bls + (wc * 64 + i * 16 + (lane & 15)) * 64 + cidx);
      }
#pragma unroll
      for (int i = 0; i < 4; i++)
#pragma unroll
        for (int j = 0; j < 4; j++)
          acc[i][j] = __builtin_amdgcn_mfma_f32_16x16x32_bf16(af[i], bfr[j], acc[i][j], 0, 0, 0);
    }
  }
}

// ---------------- fused QKV GEMM: out = gelu(A @ W^T + bias) + epilogue ----------------
// z=0: Q -> rope -> *QSCALE -> Qg[32][2048][64];  z=1: K -> rope -> Kg;  z=2: V -> Vt[32][64][2048]
// LDS 36864 B: core uses first 32768; V-transpose epilogue needs 4 waves x 9216 B = 36864 B.
__global__ __launch_bounds__(256, 4)
void gemm_qkv(const unsigned short* __restrict__ Xq, const unsigned short* __restrict__ Xk, const unsigned short* __restrict__ Xv,
              const unsigned short* __restrict__ Wqb, const unsigned short* __restrict__ Wkb, const unsigned short* __restrict__ Wvb,
              const float* __restrict__ bq, const float* __restrict__ bk, const float* __restrict__ bv,
              unsigned short* __restrict__ Qg, unsigned short* __restrict__ Kg, unsigned short* __restrict__ Vtb,
              const float2* __restrict__ rtab)
{
  __shared__ __align__(16) char lds_raw[36864];
  const int z = blockIdx.z;
  const unsigned short* A = z == 0 ? Xq : z == 1 ? Xk : Xv;
  const unsigned short* W = z == 0 ? Wqb : z == 1 ? Wkb : Wvb;
  const float* bias = z == 0 ? bq : z == 1 ? bk : bv;
  unsigned short* outB = z == 0 ? Qg : z == 1 ? Kg : Vtb;

  const int tid = threadIdx.x, lane = tid & 63, wid = tid >> 6;
  const int wr = wid >> 1, wc = wid & 1;
  const int m0 = blockIdx.x * 128, n0 = blockIdx.y * 128;

  f32x4 acc[4][4];
#pragma unroll
  for (int i = 0; i < 4; i++)
#pragma unroll
    for (int j = 0; j < 4; j++)
#pragma unroll
      for (int r = 0; r < 4; r++) acc[i][j][r] = 0.0f;

  gemm_core128(A, W, m0, n0, lds_raw, acc, lane, wid, wr, wc);
  __syncthreads();

  if (z == 2){ // V transpose via LDS -> Vt[32][64][2048]
    unsigned short* Tb = (unsigned short*)lds_raw + wid * 4608; // [64][72] per wave, 9216 B
#pragma unroll
    for (int i = 0; i < 4; i++)
#pragma unroll
      for (int j = 0; j < 4; j++){
        int n = n0 + wc * 64 + j * 16 + (lane & 15);
        float b = bias[n];
#pragma unroll
        for (int r = 0; r < 4; r++){
          int il = i * 16 + (lane >> 4) * 4 + r;
          Tb[il * 72 + j * 16 + (lane & 15)] = f2bf(gelu_exact(acc[i][j][r] + b));
        }
      }
    __syncthreads();
    int mbase = m0 + wr * 64;
    int hh = (n0 + wc * 64) >> 6;
    int t = lane;
    int i0 = ((mbase >> 11) << 10) + ((mbase & 2047) >> 1);
#pragma unroll
    for (int p = 0; p < 2; p++){
      unsigned short* dst = outB + ((size_t)((hh + (p << 4)) * 64 + t)) * 2048 + i0;
#pragma unroll
      for (int g = 0; g < 8; g++){
        ushort4 pk;
        pk.x = Tb[(p + (g * 4 + 0) * 2) * 72 + t];
        pk.y = Tb[(p + (g * 4 + 1) * 2) * 72 + t];
        pk.z = Tb[(p + (g * 4 + 2) * 2) * 72 + t];
        pk.w = Tb[(p + (g * 4 + 3) * 2) * 72 + t];
        *(ushort4*)(dst + g * 4) = pk;
      }
    }
  } else { // rope + scatter
    float scale = (z == 0) ? QSCALE : 1.0f;
#pragma unroll
    for (int i = 0; i < 4; i++)
#pragma unroll
      for (int j = 0; j < 4; j++){
        int n = n0 + wc * 64 + j * 16 + (lane & 15);
        float b = bias[n];
#pragma unroll
        for (int r = 0; r < 4; r++){
          int m = m0 + wr * 64 + i * 16 + (lane >> 4) * 4 + r;
          float val = gelu_exact(acc[i][j][r] + b);
          float pv = __shfl_xor(val, 1);
          int st = m & 2047;
          float2 cs = rtab[st * 32 + ((n >> 1) & 31)];
          float out = ((n & 1) == 0) ? (val * cs.x - pv * cs.y) : (val * cs.x + pv * cs.y);
          out *= scale;
          int nh = ((n >> 6) & 15) + ((st & 1) << 4);
          int ii = ((m >> 11) << 10) + (st >> 1);
          outB[(nh * 2048 + ii) * 64 + (n & 63)] = f2bf(out);
        }
      }
  }
}

// ---------------- final GEMM: d_out = gelu(aO @ Wo^T + bo), fp32 out ----------------
__global__ __launch_bounds__(256, 4)
void gemm_o(const unsigned short* __restrict__ A, const unsigned short* __restrict__ W,
            const float* __restrict__ bias, float* __restrict__ outF)
{
  __shared__ __align__(16) char lds_raw[32768];
  const int tid = threadIdx.x, lane = tid & 63, wid = tid >> 6;
  const int wr = wid >> 1, wc = wid & 1;
  const int m0 = blockIdx.x * 128, n0 = blockIdx.y * 128;

  f32x4 acc[4][4];
#pragma unroll
  for (int i = 0; i < 4; i++)
#pragma unroll
    for (int j = 0; j < 4; j++)
#pragma unroll
      for (int r = 0; r < 4; r++) acc[i][j][r] = 0.0f;

  gemm_core128(A, W, m0, n0, lds_raw, acc, lane, wid, wr, wc);

#pragma unroll
  for (int i = 0; i < 4; i++)
#pragma unroll
    for (int j = 0; j < 4; j++){
      int n = n0 + wc * 64 + j * 16 + (lane & 15);
      float b = bias[n];
#pragma unroll
      for (int r = 0; r < 4; r++){
        int m = m0 + wr * 64 + i * 16 + (lane >> 4) * 4 + r;
        outF[m * 1024 + n] = gelu_exact(acc[i][j][r] + b);
      }
    }
}

// ---------------- flash attention: direct-global frags + REGISTER ping-pong prefetch ----------------
// Qg/Kg [32][2048][64] bf16 (Q pre-scaled by log2e/32), Vt [32][64][2048] bf16.
// Fixed-reference softmax (bounded scores, shift invariance): P = exp2(S), l additive.
// No LDS, no barriers. Tile k+1's 16 frag loads issue before tile k's compute:
// load->use distance = one full tile (~1300 cyc) >> L2 latency (~200 cyc).
__global__ __launch_bounds__(256)
void attn_kernel(const unsigned short* __restrict__ Qg,
                 const unsigned short* __restrict__ Kg,
                 const unsigned short* __restrict__ Vt,
                 unsigned short* __restrict__ attnO)
{
  const int tid = threadIdx.x, lane = tid & 63, wid = tid >> 6;
  const int q31 = lane & 31, h = lane >> 5;
  const int bid = blockIdx.x;
  const int n = (bid & 7) * 4 + ((bid >> 3) >> 4);   // 4 groups per XCD -> KV fits L2
  const int qtile = (bid >> 3) & 15;
  const int qbase = qtile * 128;
  const unsigned short* Qn = Qg + (size_t)n * 2048 * 64;
  const unsigned short* Kn = Kg + (size_t)n * 2048 * 64;
  const unsigned short* Vn = Vt + (size_t)n * 64 * 2048;

  short8 qf[4];
  {
    int qrow = qbase + wid * 32 + q31;
#pragma unroll
    for (int c = 0; c < 4; c++)
      qf[c] = *(const short8*)(Qn + qrow * 64 + c * 16 + h * 8);
  }
  f32x16 o0, o1, lsum;
#pragma unroll
  for (int r = 0; r < 16; r++){ o0[r] = 0.0f; o1[r] = 0.0f; lsum[r] = 0.0f; }

  // per-lane K/V fragment base pointers
  const unsigned short* K0 = Kn + q31 * 64;            // + kb*64 + sl*8
  const unsigned short* K1 = Kn + (32 + q31) * 64;
  const unsigned short* V0 = Vn + (size_t)q31 * 2048;  // + kb + sl*8
  const unsigned short* V1 = Vn + (size_t)(32 + q31) * 2048;

  auto loadKV = [&](short8 (&k0)[4], short8 (&k1)[4], short8 (&v0)[4], short8 (&v1)[4], int kbx){
#pragma unroll
    for (int c = 0; c < 4; c++){
      int sl = (c << 1) | h;
      k0[c] = *(const short8*)(K0 + kbx * 64 + sl * 8);
      k1[c] = *(const short8*)(K1 + kbx * 64 + sl * 8);
      v0[c] = *(const short8*)(V0 + kbx + sl * 8);
      v1[c] = *(const short8*)(V1 + kbx + sl * 8);
    }
  };

  auto compute = [&](short8 (&k0)[4], short8 (&k1)[4], short8 (&v0)[4], short8 (&v1)[4]){
    f32x16 s0, s1;
#pragma unroll
    for (int r = 0; r < 16; r++){ s0[r] = 0.0f; s1[r] = 0.0f; }
    __builtin_amdgcn_s_setprio(1);
#pragma unroll
    for (int c = 0; c < 4; c++){
      s0 = __builtin_amdgcn_mfma_f32_32x32x16_bf16(k0[c], qf[c], s0, 0, 0, 0);
      s1 = __builtin_amdgcn_mfma_f32_32x32x16_bf16(k1[c], qf[c], s1, 0, 0, 0);
    }
    __builtin_amdgcn_s_setprio(0);
#pragma unroll
    for (int r = 0; r < 16; r++) s0[r] = exp2f(s0[r]);
#pragma unroll
    for (int r = 0; r < 16; r++) s1[r] = exp2f(s1[r]);
    lsum += s0;
    lsum += s1;
    __builtin_amdgcn_s_setprio(1);
#pragma unroll
    for (int kc = 0; kc < 4; kc++){
      const f32x16& S = (kc < 2) ? s0 : s1;
      const int rb = (kc & 1) * 8;
      unsigned a0, a1, b0, b1;
      asm("v_cvt_pk_bf16_f32 %0, %1, %2" : "=v"(a0) : "v"(S[rb + 0]), "v"(S[rb + 1]));
      asm("v_cvt_pk_bf16_f32 %0, %1, %2" : "=v"(a1) : "v"(S[rb + 2]), "v"(S[rb + 3]));
      asm("v_cvt_pk_bf16_f32 %0, %1, %2" : "=v"(b0) : "v"(S[rb + 4]), "v"(S[rb + 5]));
      asm("v_cvt_pk_bf16_f32 %0, %1, %2" : "=v"(b1) : "v"(S[rb + 6]), "v"(S[rb + 7]));
      asm("v_permlane32_swap_b32 %0, %1" : "+v"(a0), "+v"(b0));
      asm("v_permlane32_swap_b32 %0, %1" : "+v"(a1), "+v"(b1));
      union { int i[4]; short8 s; } u;
      u.i[0] = (int)a0; u.i[1] = (int)a1; u.i[2] = (int)b0; u.i[3] = (int)b1;
      short8 pf = u.s;
      o0 = __builtin_amdgcn_mfma_f32_32x32x16_bf16(v0[kc], pf, o0, 0, 0, 0);
      o1 = __builtin_amdgcn_mfma_f32_32x32x16_bf16(v1[kc], pf, o1, 0, 0, 0);
    }
    __builtin_amdgcn_s_setprio(0);
  };

  short8 kA0[4], kA1[4], vA0[4], vA1[4];
  short8 kB0[4], kB1[4], vB0[4], vB1[4];
  loadKV(kA0, kA1, vA0, vA1, 0);
  for (int kb = 0; kb < 2048; kb += 128){
    loadKV(kB0, kB1, vB0, vB1, kb + 64);              // prefetch tile kb+64
    compute(kA0, kA1, vA0, vA1);                      // compute tile kb
    loadKV(kA0, kA1, vA0, vA1, (kb + 128) & 2047);    // prefetch tile kb+128 (wraps at end)
    compute(kB0, kB1, vB0, vB1);                      // compute tile kb+64
  }

  // final l: reduce lsum vector, then combine the two key-half lanes
  float l = 0.0f;
#pragma unroll
  for (int r = 0; r < 16; r++) l += lsum[r];
  l += __shfl_xor(l, 32);
  // epilogue: O^T -> natural token rows
  float rl = 1.0f / l;
  const int p_par = n >> 4, head = n & 15;
  int ig = qbase + wid * 32 + q31;
  size_t rbase = ((size_t)(((ig >> 10) << 11) + ((ig & 1023) << 1) + p_par)) * 1024 + head * 64;
#pragma unroll
  for (int r = 0; r < 16; r++){
    int dl = (r & 3) + 8 * (r >> 2) + 4 * h;
    attnO[rbase + dl]      = f2bf(o0[r] * rl);
    attnO[rbase + 32 + dl] = f2bf(o1[r] * rl);
  }
}

// ---------------- launch ----------------
extern "C" void kernel_launch(void* const* d_in, const int* in_sizes, int n_in,
                              void* d_out, int out_size, void* d_ws, size_t ws_size,
                              hipStream_t stream)
{
  const float* q  = (const float*)d_in[0];
  const float* k  = (const float*)d_in[1];
  const float* v  = (const float*)d_in[2];
  const float* Wq = (const float*)d_in[3];
  const float* bq = (const float*)d_in[4];
  const float* Wk = (const float*)d_in[5];
  const float* bk = (const float*)d_in[6];
  const float* Wv = (const float*)d_in[7];
  const float* bv = (const float*)d_in[8];
  const float* Wo = (const float*)d_in[9];
  const float* bo = (const float*)d_in[10];

  char* ws = (char*)d_ws;
  size_t off = 0;
  auto alloc = [&](size_t bytes) -> void* {
    void* p = ws + off;
    off += (bytes + 255) & ~(size_t)255;
    return p;
  };
  unsigned short* Xq  = (unsigned short*)alloc(4194304ull * 2);
  unsigned short* Xk  = (unsigned short*)alloc(4194304ull * 2);
  unsigned short* Xv  = (unsigned short*)alloc(4194304ull * 2);
  unsigned short* Wqb = (unsigned short*)alloc(1048576ull * 2);
  unsigned short* Wkb = (unsigned short*)alloc(1048576ull * 2);
  unsigned short* Wvb = (unsigned short*)alloc(1048576ull * 2);
  unsigned short* Wob = (unsigned short*)alloc(1048576ull * 2);
  unsigned short* Qg  = (unsigned short*)alloc(4194304ull * 2);
  unsigned short* Kg  = (unsigned short*)alloc(4194304ull * 2);
  unsigned short* Vtb = (unsigned short*)alloc(4194304ull * 2);
  unsigned short* aO  = (unsigned short*)alloc(4194304ull * 2);
  float2*         rtab = (float2*)alloc(2048ull * 32 * 8);

  ConvArgs ca;
  const float* srcs[7] = {q, k, v, Wq, Wk, Wv, Wo};
  unsigned short* dsts[7] = {Xq, Xk, Xv, Wqb, Wkb, Wvb, Wob};
  int ns[7] = {4194304, 4194304, 4194304, 1048576, 1048576, 1048576, 1048576};
  for (int i = 0; i < 7; i++){ ca.src[i] = srcs[i]; ca.dst[i] = dsts[i]; ca.n[i] = ns[i]; }

  conv_kernel<<<dim3(4096, 7), 256, 0, stream>>>(ca);
  rope_kernel<<<dim3(256), 256, 0, stream>>>(rtab);
  gemm_qkv<<<dim3(32, 8, 3), 256, 0, stream>>>(Xq, Xk, Xv, Wqb, Wkb, Wvb, bq, bk, bv, Qg, Kg, Vtb, rtab);
  attn_kernel<<<dim3(512), 256, 0, stream>>>(Qg, Kg, Vtb, aO);
  gemm_o<<<dim3(32, 8), 256, 0, stream>>>(aO, Wob, bo, (float*)d_out);
}

// Round 10
// 169.128 us; speedup vs baseline: 1.1986x; 1.1986x over previous
//
#include <hip/hip_runtime.h>
#include <hip/hip_bf16.h>
#include <stdint.h>

typedef __attribute__((ext_vector_type(4))) float f32x4;
typedef __attribute__((ext_vector_type(16))) float f32x16;
typedef __attribute__((ext_vector_type(8))) short short8;
typedef __attribute__((ext_vector_type(4))) short short4v;

#define DEV __device__ __forceinline__

DEV unsigned short f2bf(float f){
  unsigned u = __float_as_uint(f);
  u += 0x7FFFu + ((u >> 16) & 1u);
  return (unsigned short)(u >> 16);
}
// branch-free erf, Abramowitz-Stegun 7.1.26, |err| <= 1.5e-7
DEV float erf_fast(float x){
  float ax = fabsf(x);
  float t = 1.0f / (1.0f + 0.3275911f * ax);
  float p = t * (0.254829592f + t * (-0.284496736f + t * (1.421413741f +
            t * (-1.453152027f + t * 1.061405429f))));
  float r = 1.0f - p * __expf(-ax * ax);
  return copysignf(r, x);
}
DEV float gelu_exact(float x){ return 0.5f * x * (1.0f + erf_fast(x * 0.70710678118654752f)); }

DEV float exp2_fast(float x){
#if __has_builtin(__builtin_amdgcn_exp2f)
  return __builtin_amdgcn_exp2f(x);   // scores bounded: no denormal/overflow concerns
#else
  return exp2f(x);
#endif
}

DEV void gl_lds16(const void* g, void* l){
  __builtin_amdgcn_global_load_lds((const __attribute__((address_space(1))) unsigned int*)g,
                                   (__attribute__((address_space(3))) unsigned int*)l, 16, 0, 0);
}

// scale folded into Q: sqrt(1/1024) * log2(e)  -> softmax in exp2 units
#define QSCALE 0.04508422f

// ---------------- conversion fp32 -> bf16 ----------------
struct ConvArgs { const float* src[7]; unsigned short* dst[7]; int n[7]; };

__global__ __launch_bounds__(256) void conv_kernel(ConvArgs a){
  int t = blockIdx.y;
  int i = (blockIdx.x * 256 + threadIdx.x) * 4;
  if (i >= a.n[t]) return;
  float4 v = *(const float4*)(a.src[t] + i);
  ushort4 o;
  o.x = f2bf(v.x); o.y = f2bf(v.y); o.z = f2bf(v.z); o.w = f2bf(v.w);
  *(ushort4*)(a.dst[t] + i) = o;
}

// ---------------- rope table: cos/sin [2048][32] ----------------
__global__ __launch_bounds__(256) void rope_kernel(float2* tab){
  int g = blockIdx.x * 256 + threadIdx.x;
  if (g >= 2048 * 32) return;
  int s = g >> 5, j = g & 31;
  float theta = (float)exp(-(double)j * (9.210340371976184 / 32.0)); // 10000^(-j/32)
  double ang = (double)s * (double)theta;
  tab[g] = make_float2((float)cos(ang), (float)sin(ang));
}

// ============ 128x128 tile GEMM core: BK=64, SINGLE 32KB buffer, 4 waves ============
DEV void gemm_core128(const unsigned short* __restrict__ A, const unsigned short* __restrict__ W,
                      int m0, int n0, char* lds_raw, f32x4 (&acc)[4][4],
                      int lane, int wid, int wr, int wc)
{
  const int srow = wid * 8 + (lane >> 3);
  const int scc  = ((lane & 7) ^ (lane >> 3)) * 8;
  const int rxor = lane & 7;

  for (int kt = 0; kt < 16; ++kt){
    int kk = kt * 64;
    __syncthreads();
#pragma unroll
    for (int t = 0; t < 4; t++){
      gl_lds16(A + (size_t)(m0 + t * 32 + srow) * 1024 + kk + scc,
               lds_raw + (t * 2048 + wid * 512) * 2);
      gl_lds16(W + (size_t)(n0 + t * 32 + srow) * 1024 + kk + scc,
               lds_raw + 16384 + (t * 2048 + wid * 512) * 2);
    }
    __syncthreads();
    const unsigned short* Als = (const unsigned short*)lds_raw;
    const unsigned short* Bls = Als + 8192;
#pragma unroll
    for (int dk = 0; dk < 2; ++dk){
      short8 af[4], bfr[4];
      int cidx = (((dk * 4 + (lane >> 4)) ^ rxor) << 3);
#pragma unroll
      for (int i = 0; i < 4; i++){
        af[i]  = *(const short8*)(Als + (wr * 64 + i * 16 + (lane & 15)) * 64 + cidx);
        bfr[i] = *(const short8*)(Bls + (wc * 64 + i * 16 + (lane & 15)) * 64 + cidx);
      }
#pragma unroll
      for (int i = 0; i < 4; i++)
#pragma unroll
        for (int j = 0; j < 4; j++)
          acc[i][j] = __builtin_amdgcn_mfma_f32_16x16x32_bf16(af[i], bfr[j], acc[i][j], 0, 0, 0);
    }
  }
}

// ---------------- fused QKV GEMM (unchanged from R7) ----------------
__global__ __launch_bounds__(256, 4)
void gemm_qkv(const unsigned short* __restrict__ Xq, const unsigned short* __restrict__ Xk, const unsigned short* __restrict__ Xv,
              const unsigned short* __restrict__ Wqb, const unsigned short* __restrict__ Wkb, const unsigned short* __restrict__ Wvb,
              const float* __restrict__ bq, const float* __restrict__ bk, const float* __restrict__ bv,
              unsigned short* __restrict__ Qg, unsigned short* __restrict__ Kg, unsigned short* __restrict__ Vtb,
              const float2* __restrict__ rtab)
{
  __shared__ __align__(16) char lds_raw[36864];
  const int z = blockIdx.z;
  const unsigned short* A = z == 0 ? Xq : z == 1 ? Xk : Xv;
  const unsigned short* W = z == 0 ? Wqb : z == 1 ? Wkb : Wvb;
  const float* bias = z == 0 ? bq : z == 1 ? bk : bv;
  unsigned short* outB = z == 0 ? Qg : z == 1 ? Kg : Vtb;

  const int tid = threadIdx.x, lane = tid & 63, wid = tid >> 6;
  const int wr = wid >> 1, wc = wid & 1;
  const int m0 = blockIdx.x * 128, n0 = blockIdx.y * 128;

  f32x4 acc[4][4];
#pragma unroll
  for (int i = 0; i < 4; i++)
#pragma unroll
    for (int j = 0; j < 4; j++)
#pragma unroll
      for (int r = 0; r < 4; r++) acc[i][j][r] = 0.0f;

  gemm_core128(A, W, m0, n0, lds_raw, acc, lane, wid, wr, wc);
  __syncthreads();

  if (z == 2){ // V transpose via LDS -> Vt[32][64][2048]
    unsigned short* Tb = (unsigned short*)lds_raw + wid * 4608;
#pragma unroll
    for (int i = 0; i < 4; i++)
#pragma unroll
      for (int j = 0; j < 4; j++){
        int n = n0 + wc * 64 + j * 16 + (lane & 15);
        float b = bias[n];
#pragma unroll
        for (int r = 0; r < 4; r++){
          int il = i * 16 + (lane >> 4) * 4 + r;
          Tb[il * 72 + j * 16 + (lane & 15)] = f2bf(gelu_exact(acc[i][j][r] + b));
        }
      }
    __syncthreads();
    int mbase = m0 + wr * 64;
    int hh = (n0 + wc * 64) >> 6;
    int t = lane;
    int i0 = ((mbase >> 11) << 10) + ((mbase & 2047) >> 1);
#pragma unroll
    for (int p = 0; p < 2; p++){
      unsigned short* dst = outB + ((size_t)((hh + (p << 4)) * 64 + t)) * 2048 + i0;
#pragma unroll
      for (int g = 0; g < 8; g++){
        ushort4 pk;
        pk.x = Tb[(p + (g * 4 + 0) * 2) * 72 + t];
        pk.y = Tb[(p + (g * 4 + 1) * 2) * 72 + t];
        pk.z = Tb[(p + (g * 4 + 2) * 2) * 72 + t];
        pk.w = Tb[(p + (g * 4 + 3) * 2) * 72 + t];
        *(ushort4*)(dst + g * 4) = pk;
      }
    }
  } else { // rope + scatter
    float scale = (z == 0) ? QSCALE : 1.0f;
#pragma unroll
    for (int i = 0; i < 4; i++)
#pragma unroll
      for (int j = 0; j < 4; j++){
        int n = n0 + wc * 64 + j * 16 + (lane & 15);
        float b = bias[n];
#pragma unroll
        for (int r = 0; r < 4; r++){
          int m = m0 + wr * 64 + i * 16 + (lane >> 4) * 4 + r;
          float val = gelu_exact(acc[i][j][r] + b);
          float pv = __shfl_xor(val, 1);
          int st = m & 2047;
          float2 cs = rtab[st * 32 + ((n >> 1) & 31)];
          float out = ((n & 1) == 0) ? (val * cs.x - pv * cs.y) : (val * cs.x + pv * cs.y);
          out *= scale;
          int nh = ((n >> 6) & 15) + ((st & 1) << 4);
          int ii = ((m >> 11) << 10) + (st >> 1);
          outB[(nh * 2048 + ii) * 64 + (n & 63)] = f2bf(out);
        }
      }
  }
}

// ---------------- final GEMM: d_out = gelu(aOg @ Wo^T + bo), fp32 out ----------------
// A is in GROUP layout aOg[32 n][2048 iq][64 d]; natural (row m, col k) maps to
// n = (k>>6) + 16*(m&1), iq = ((m>>11)<<10) + ((m&2047)>>1), d = k&63. Since BK=64,
// head = kt exactly -> gather is just a per-(row,kt) base change in staging.
__global__ __launch_bounds__(256, 4)
void gemm_o(const unsigned short* __restrict__ aOg, const unsigned short* __restrict__ W,
            const float* __restrict__ bias, float* __restrict__ outF)
{
  __shared__ __align__(16) char lds_raw[32768];
  const int tid = threadIdx.x, lane = tid & 63, wid = tid >> 6;
  const int wr = wid >> 1, wc = wid & 1;
  const int m0 = blockIdx.x * 128, n0 = blockIdx.y * 128;

  f32x4 acc[4][4];
#pragma unroll
  for (int i = 0; i < 4; i++)
#pragma unroll
    for (int j = 0; j < 4; j++)
#pragma unroll
      for (int r = 0; r < 4; r++) acc[i][j][r] = 0.0f;

  const int srow = wid * 8 + (lane >> 3);
  const int scc  = ((lane & 7) ^ (lane >> 3)) * 8;
  const int rxor = lane & 7;

  for (int kt = 0; kt < 16; ++kt){
    int kk = kt * 64;
    __syncthreads();
#pragma unroll
    for (int t = 0; t < 4; t++){
      int row = m0 + t * 32 + srow;
      int nn = kt + ((row & 1) << 4);
      int iq = ((row >> 11) << 10) + ((row & 2047) >> 1);
      gl_lds16(aOg + ((size_t)nn * 2048 + iq) * 64 + scc,
               lds_raw + (t * 2048 + wid * 512) * 2);
      gl_lds16(W + (size_t)(n0 + t * 32 + srow) * 1024 + kk + scc,
               lds_raw + 16384 + (t * 2048 + wid * 512) * 2);
    }
    __syncthreads();
    const unsigned short* Als = (const unsigned short*)lds_raw;
    const unsigned short* Bls = Als + 8192;
#pragma unroll
    for (int dk = 0; dk < 2; ++dk){
      short8 af[4], bfr[4];
      int cidx = (((dk * 4 + (lane >> 4)) ^ rxor) << 3);
#pragma unroll
      for (int i = 0; i < 4; i++){
        af[i]  = *(const short8*)(Als + (wr * 64 + i * 16 + (lane & 15)) * 64 + cidx);
        bfr[i] = *(const short8*)(Bls + (wc * 64 + i * 16 + (lane & 15)) * 64 + cidx);
      }
#pragma unroll
      for (int i = 0; i < 4; i++)
#pragma unroll
        for (int j = 0; j < 4; j++)
          acc[i][j] = __builtin_amdgcn_mfma_f32_16x16x32_bf16(af[i], bfr[j], acc[i][j], 0, 0, 0);
    }
  }
#pragma unroll
  for (int i = 0; i < 4; i++)
#pragma unroll
    for (int j = 0; j < 4; j++){
      int n = n0 + wc * 64 + j * 16 + (lane & 15);
      float b = bias[n];
#pragma unroll
      for (int r = 0; r < 4; r++){
        int m = m0 + wr * 64 + i * 16 + (lane >> 4) * 4 + r;
        outF[m * 1024 + n] = gelu_exact(acc[i][j][r] + b);
      }
    }
}

// ---------------- flash attention (R7 LDS structure) + KV-split + ones-trick l ----------------
// SPLIT=1: whole KV, writes bf16 aOg[n][iq][d] directly.
// SPLIT=2: half KV per block, writes fp32 partial O (d-major [kvh][n][d][iq]) + partial l.
// l computed on the MFMA pipe: l_acc = mfma(ones, pf, l_acc) -> all rows = sum_k P.
template<int SPLIT>
__global__ __launch_bounds__(256, 4)
void attn_kernel(const unsigned short* __restrict__ Qg,
                 const unsigned short* __restrict__ Kg,
                 const unsigned short* __restrict__ Vt,
                 unsigned short* __restrict__ aOg,
                 float* __restrict__ Opart, float* __restrict__ Lpart)
{
  __shared__ __align__(16) char lds_raw[16384];
  unsigned short* Kls = (unsigned short*)lds_raw;
  unsigned short* Vls = (unsigned short*)(lds_raw + 8192);
  const int tid = threadIdx.x, lane = tid & 63, wid = tid >> 6;
  const int q31 = lane & 31, h = lane >> 5;
  const int bid = blockIdx.x;
  int n, qtile, kvh;
  if (SPLIT == 2){
    int y = bid >> 3;
    n = (bid & 7) * 4 + (y >> 5);
    qtile = (y & 31) >> 1;
    kvh = y & 1;
  } else {
    n = (bid & 7) * 4 + ((bid >> 3) >> 4);
    qtile = (bid >> 3) & 15;
    kvh = 0;
  }
  const int qbase = qtile * 128;
  const int kb0 = kvh * (2048 / SPLIT), kbN = kb0 + 2048 / SPLIT;
  const unsigned short* Qn = Qg + (size_t)n * 2048 * 64;
  const unsigned short* Kn = Kg + (size_t)n * 2048 * 64;
  const unsigned short* Vn = Vt + (size_t)n * 64 * 2048;

  short8 qf[4];
  {
    int qrow = qbase + wid * 32 + q31;
#pragma unroll
    for (int c = 0; c < 4; c++)
      qf[c] = *(const short8*)(Qn + qrow * 64 + c * 16 + h * 8);
  }
  short8 ones;
#pragma unroll
  for (int i = 0; i < 8; i++) ones[i] = (short)0x3F80;  // bf16 1.0

  f32x16 o0, o1, l_acc;
#pragma unroll
  for (int r = 0; r < 16; r++){ o0[r] = 0.0f; o1[r] = 0.0f; l_acc[r] = 0.0f; }

  short8 rk[2], rv[2];
#pragma unroll
  for (int t = 0; t < 2; t++){
    int chunk = t * 256 + tid, row = chunk >> 3, c = chunk & 7;
    rk[t] = *(const short8*)(Kn + (kb0 + row) * 64 + c * 8);
    rv[t] = *(const short8*)(Vn + row * 2048 + kb0 + c * 8);
  }

  for (int kb = kb0; kb < kbN; kb += 64){
    __syncthreads();
#pragma unroll
    for (int t = 0; t < 2; t++){
      int chunk = t * 256 + tid, row = chunk >> 3, c = chunk & 7;
      int sw = ((c ^ (row & 7)) << 3);
      *(short8*)(Kls + row * 64 + sw) = rk[t];
      *(short8*)(Vls + row * 64 + sw) = rv[t];
    }
    __syncthreads();
    if (kb + 64 < kbN){
#pragma unroll
      for (int t = 0; t < 2; t++){
        int chunk = t * 256 + tid, row = chunk >> 3, c = chunk & 7;
        rk[t] = *(const short8*)(Kn + (kb + 64 + row) * 64 + c * 8);
        rv[t] = *(const short8*)(Vn + row * 2048 + kb + 64 + c * 8);
      }
    }
    // S^T = K * Q
    f32x16 s0, s1;
#pragma unroll
    for (int r = 0; r < 16; r++){ s0[r] = 0.0f; s1[r] = 0.0f; }
    __builtin_amdgcn_s_setprio(1);
#pragma unroll
    for (int c = 0; c < 4; c++){
      int sl = (c << 1) | h;
      short8 kf0 = *(const short8*)(Kls + q31 * 64 + ((sl ^ (q31 & 7)) << 3));
      s0 = __builtin_amdgcn_mfma_f32_32x32x16_bf16(kf0, qf[c], s0, 0, 0, 0);
      short8 kf1 = *(const short8*)(Kls + (32 + q31) * 64 + ((sl ^ (q31 & 7)) << 3));
      s1 = __builtin_amdgcn_mfma_f32_32x32x16_bf16(kf1, qf[c], s1, 0, 0, 0);
    }
    __builtin_amdgcn_s_setprio(0);
    // P = exp2(S), fixed reference 0 (scores bounded)
#pragma unroll
    for (int r = 0; r < 16; r++) s0[r] = exp2_fast(s0[r]);
#pragma unroll
    for (int r = 0; r < 16; r++) s1[r] = exp2_fast(s1[r]);
    // pack P -> bf16 B-frags; PV + l on MFMA pipe
    __builtin_amdgcn_s_setprio(1);
#pragma unroll
    for (int kc = 0; kc < 4; kc++){
      const f32x16& S = (kc < 2) ? s0 : s1;
      const int rb = (kc & 1) * 8;
      unsigned a0, a1, b0, b1;
      asm("v_cvt_pk_bf16_f32 %0, %1, %2" : "=v"(a0) : "v"(S[rb + 0]), "v"(S[rb + 1]));
      asm("v_cvt_pk_bf16_f32 %0, %1, %2" : "=v"(a1) : "v"(S[rb + 2]), "v"(S[rb + 3]));
      asm("v_cvt_pk_bf16_f32 %0, %1, %2" : "=v"(b0) : "v"(S[rb + 4]), "v"(S[rb + 5]));
      asm("v_cvt_pk_bf16_f32 %0, %1, %2" : "=v"(b1) : "v"(S[rb + 6]), "v"(S[rb + 7]));
      asm("v_permlane32_swap_b32 %0, %1" : "+v"(a0), "+v"(b0));
      asm("v_permlane32_swap_b32 %0, %1" : "+v"(a1), "+v"(b1));
      union { int i[4]; short8 s; } u;
      u.i[0] = (int)a0; u.i[1] = (int)a1; u.i[2] = (int)b0; u.i[3] = (int)b1;
      short8 pf = u.s;
      int sl = (kc << 1) | h;
      {
        short8 vf = *(const short8*)(Vls + q31 * 64 + ((sl ^ (q31 & 7)) << 3));
        o0 = __builtin_amdgcn_mfma_f32_32x32x16_bf16(vf, pf, o0, 0, 0, 0);
      }
      {
        int dr = 32 + q31;
        short8 vf = *(const short8*)(Vls + dr * 64 + ((sl ^ (dr & 7)) << 3));
        o1 = __builtin_amdgcn_mfma_f32_32x32x16_bf16(vf, pf, o1, 0, 0, 0);
      }
      l_acc = __builtin_amdgcn_mfma_f32_32x32x16_bf16(ones, pf, l_acc, 0, 0, 0);
    }
    __builtin_amdgcn_s_setprio(0);
  }

  const float l = l_acc[0];   // all rows identical = sum over all keys this block saw
  const int iq = qbase + wid * 32 + q31;

  if (SPLIT == 2){
    // unnormalized partials, d-major for coalescing: Opart[kvh][n][d][iq]
    float* Ob = Opart + ((size_t)(kvh * 32 + n) * 64) * 2048;
#pragma unroll
    for (int r = 0; r < 16; r++){
      int dl = (r & 3) + 8 * (r >> 2) + 4 * h;
      Ob[(size_t)dl * 2048 + iq] = o0[r];
      Ob[(size_t)(32 + dl) * 2048 + iq] = o1[r];
    }
    if (h == 0) Lpart[(size_t)(kvh * 32 + n) * 2048 + iq] = l;
  } else {
    float rl = 1.0f / l;
    unsigned short* dst = aOg + ((size_t)n * 2048 + iq) * 64;
#pragma unroll
    for (int r = 0; r < 16; r++){
      int dl = (r & 3) + 8 * (r >> 2) + 4 * h;
      dst[dl]      = f2bf(o0[r] * rl);
      dst[32 + dl] = f2bf(o1[r] * rl);
    }
  }
}

// ---------------- combine partials: aOg[n][iq][d] = (O0+O1)/(l0+l1) ----------------
// grid 1024 = 32 groups x 32 iq-tiles of 64; LDS transpose for coalesced writes.
__global__ __launch_bounds__(256)
void norm_kernel(const float* __restrict__ Opart, const float* __restrict__ Lpart,
                 unsigned short* __restrict__ aOg)
{
  __shared__ unsigned short Tls[64 * 72];
  const int n = blockIdx.x >> 5, iq0 = (blockIdx.x & 31) * 64;
  const int tid = threadIdx.x;
  const int iql = tid & 63, dg = tid >> 6;   // dg 0..3 -> d = dg*16 .. +15
  float l = Lpart[(size_t)n * 2048 + iq0 + iql] + Lpart[(size_t)(32 + n) * 2048 + iq0 + iql];
  float rl = 1.0f / l;
  const float* O0 = Opart + ((size_t)n * 64) * 2048;
  const float* O1 = Opart + ((size_t)(32 + n) * 64) * 2048;
#pragma unroll
  for (int dd = 0; dd < 16; dd++){
    int d = dg * 16 + dd;
    float v = O0[(size_t)d * 2048 + iq0 + iql] + O1[(size_t)d * 2048 + iq0 + iql];
    Tls[iql * 72 + d] = f2bf(v * rl);
  }
  __syncthreads();
  const int iqr = tid >> 2, db = (tid & 3) * 16;
  unsigned short* dst = aOg + ((size_t)n * 2048 + iq0 + iqr) * 64 + db;
  *(short8*)(dst)     = *(const short8*)(Tls + iqr * 72 + db);
  *(short8*)(dst + 8) = *(const short8*)(Tls + iqr * 72 + db + 8);
}

// ---------------- launch ----------------
extern "C" void kernel_launch(void* const* d_in, const int* in_sizes, int n_in,
                              void* d_out, int out_size, void* d_ws, size_t ws_size,
                              hipStream_t stream)
{
  const float* q  = (const float*)d_in[0];
  const float* k  = (const float*)d_in[1];
  const float* v  = (const float*)d_in[2];
  const float* Wq = (const float*)d_in[3];
  const float* bq = (const float*)d_in[4];
  const float* Wk = (const float*)d_in[5];
  const float* bk = (const float*)d_in[6];
  const float* Wv = (const float*)d_in[7];
  const float* bv = (const float*)d_in[8];
  const float* Wo = (const float*)d_in[9];
  const float* bo = (const float*)d_in[10];

  char* ws = (char*)d_ws;
  size_t off = 0;
  auto alloc = [&](size_t bytes) -> void* {
    void* p = ws + off;
    off += (bytes + 255) & ~(size_t)255;
    return p;
  };
  unsigned short* Xq  = (unsigned short*)alloc(4194304ull * 2);
  unsigned short* Xk  = (unsigned short*)alloc(4194304ull * 2);
  unsigned short* Xv  = (unsigned short*)alloc(4194304ull * 2);
  unsigned short* Wqb = (unsigned short*)alloc(1048576ull * 2);
  unsigned short* Wkb = (unsigned short*)alloc(1048576ull * 2);
  unsigned short* Wvb = (unsigned short*)alloc(1048576ull * 2);
  unsigned short* Wob = (unsigned short*)alloc(1048576ull * 2);
  unsigned short* Qg  = (unsigned short*)alloc(4194304ull * 2);
  unsigned short* Kg  = (unsigned short*)alloc(4194304ull * 2);
  unsigned short* Vtb = (unsigned short*)alloc(4194304ull * 2);
  unsigned short* aOg = (unsigned short*)alloc(4194304ull * 2);
  float2*         rtab = (float2*)alloc(2048ull * 32 * 8);
  float*          Opart = (float*)alloc(2ull * 32 * 64 * 2048 * 4);  // 33.6 MB
  float*          Lpart = (float*)alloc(2ull * 32 * 2048 * 4);       // 0.5 MB
  const bool split2 = (off <= ws_size);

  ConvArgs ca;
  const float* srcs[7] = {q, k, v, Wq, Wk, Wv, Wo};
  unsigned short* dsts[7] = {Xq, Xk, Xv, Wqb, Wkb, Wvb, Wob};
  int ns[7] = {4194304, 4194304, 4194304, 1048576, 1048576, 1048576, 1048576};
  for (int i = 0; i < 7; i++){ ca.src[i] = srcs[i]; ca.dst[i] = dsts[i]; ca.n[i] = ns[i]; }

  conv_kernel<<<dim3(4096, 7), 256, 0, stream>>>(ca);
  rope_kernel<<<dim3(256), 256, 0, stream>>>(rtab);
  gemm_qkv<<<dim3(32, 8, 3), 256, 0, stream>>>(Xq, Xk, Xv, Wqb, Wkb, Wvb, bq, bk, bv, Qg, Kg, Vtb, rtab);
  if (split2){
    attn_kernel<2><<<dim3(1024), 256, 0, stream>>>(Qg, Kg, Vtb, aOg, Opart, Lpart);
    norm_kernel<<<dim3(1024), 256, 0, stream>>>(Opart, Lpart, aOg);
  } else {
    attn_kernel<1><<<dim3(512), 256, 0, stream>>>(Qg, Kg, Vtb, aOg, nullptr, nullptr);
  }
  gemm_o<<<dim3(32, 8), 256, 0, stream>>>(aOg, Wob, bo, (float*)d_out);
}

// Round 11
// 126.381 us; speedup vs baseline: 1.6040x; 1.3382x over previous
//
#include <hip/hip_runtime.h>
#include <hip/hip_bf16.h>
#include <stdint.h>

typedef __attribute__((ext_vector_type(4))) float f32x4;
typedef __attribute__((ext_vector_type(16))) float f32x16;
typedef __attribute__((ext_vector_type(8))) short short8;

#define DEV __device__ __forceinline__

DEV unsigned short f2bf(float f){
  unsigned u = __float_as_uint(f);
  u += 0x7FFFu + ((u >> 16) & 1u);
  return (unsigned short)(u >> 16);
}
// branch-free erf, Abramowitz-Stegun 7.1.26, |err| <= 1.5e-7
DEV float erf_fast(float x){
  float ax = fabsf(x);
  float t = 1.0f / (1.0f + 0.3275911f * ax);
  float p = t * (0.254829592f + t * (-0.284496736f + t * (1.421413741f +
            t * (-1.453152027f + t * 1.061405429f))));
  float r = 1.0f - p * __expf(-ax * ax);
  return copysignf(r, x);
}
DEV float gelu_exact(float x){ return 0.5f * x * (1.0f + erf_fast(x * 0.70710678118654752f)); }

DEV float exp2_fast(float x){
#if __has_builtin(__builtin_amdgcn_exp2f)
  return __builtin_amdgcn_exp2f(x);   // scores bounded: no denormal/overflow concerns
#else
  return exp2f(x);
#endif
}

DEV void gl_lds16(const void* g, void* l){
  __builtin_amdgcn_global_load_lds((const __attribute__((address_space(1))) unsigned int*)g,
                                   (__attribute__((address_space(3))) unsigned int*)l, 16, 0, 0);
}

// scale folded into Q: sqrt(1/1024) * log2(e)  -> softmax in exp2 units
#define QSCALE 0.04508422f

// ---------------- conversion fp32 -> bf16 ----------------
struct ConvArgs { const float* src[7]; unsigned short* dst[7]; int n[7]; };

__global__ __launch_bounds__(256) void conv_kernel(ConvArgs a){
  int t = blockIdx.y;
  int i = (blockIdx.x * 256 + threadIdx.x) * 4;
  if (i >= a.n[t]) return;
  float4 v = *(const float4*)(a.src[t] + i);
  ushort4 o;
  o.x = f2bf(v.x); o.y = f2bf(v.y); o.z = f2bf(v.z); o.w = f2bf(v.w);
  *(ushort4*)(a.dst[t] + i) = o;
}

// ---------------- rope table: cos/sin [2048][32] ----------------
__global__ __launch_bounds__(256) void rope_kernel(float2* tab){
  int g = blockIdx.x * 256 + threadIdx.x;
  if (g >= 2048 * 32) return;
  int s = g >> 5, j = g & 31;
  float theta = (float)exp(-(double)j * (9.210340371976184 / 32.0)); // 10000^(-j/32)
  double ang = (double)s * (double)theta;
  tab[g] = make_float2((float)cos(ang), (float)sin(ang));
}

// ============ 128x128 tile GEMM core: BK=64, SINGLE 32KB buffer, 4 waves ============
DEV void gemm_core128(const unsigned short* __restrict__ A, const unsigned short* __restrict__ W,
                      int m0, int n0, char* lds_raw, f32x4 (&acc)[4][4],
                      int lane, int wid, int wr, int wc)
{
  const int srow = wid * 8 + (lane >> 3);
  const int scc  = ((lane & 7) ^ (lane >> 3)) * 8;
  const int rxor = lane & 7;

  for (int kt = 0; kt < 16; ++kt){
    int kk = kt * 64;
    __syncthreads();
#pragma unroll
    for (int t = 0; t < 4; t++){
      gl_lds16(A + (size_t)(m0 + t * 32 + srow) * 1024 + kk + scc,
               lds_raw + (t * 2048 + wid * 512) * 2);
      gl_lds16(W + (size_t)(n0 + t * 32 + srow) * 1024 + kk + scc,
               lds_raw + 16384 + (t * 2048 + wid * 512) * 2);
    }
    __syncthreads();
    const unsigned short* Als = (const unsigned short*)lds_raw;
    const unsigned short* Bls = Als + 8192;
#pragma unroll
    for (int dk = 0; dk < 2; ++dk){
      short8 af[4], bfr[4];
      int cidx = (((dk * 4 + (lane >> 4)) ^ rxor) << 3);
#pragma unroll
      for (int i = 0; i < 4; i++){
        af[i]  = *(const short8*)(Als + (wr * 64 + i * 16 + (lane & 15)) * 64 + cidx);
        bfr[i] = *(const short8*)(Bls + (wc * 64 + i * 16 + (lane & 15)) * 64 + cidx);
      }
#pragma unroll
      for (int i = 0; i < 4; i++)
#pragma unroll
        for (int j = 0; j < 4; j++)
          acc[i][j] = __builtin_amdgcn_mfma_f32_16x16x32_bf16(af[i], bfr[j], acc[i][j], 0, 0, 0);
    }
  }
}

// ---------------- fused QKV GEMM ----------------
__global__ __launch_bounds__(256, 4)
void gemm_qkv(const unsigned short* __restrict__ Xq, const unsigned short* __restrict__ Xk, const unsigned short* __restrict__ Xv,
              const unsigned short* __restrict__ Wqb, const unsigned short* __restrict__ Wkb, const unsigned short* __restrict__ Wvb,
              const float* __restrict__ bq, const float* __restrict__ bk, const float* __restrict__ bv,
              unsigned short* __restrict__ Qg, unsigned short* __restrict__ Kg, unsigned short* __restrict__ Vtb,
              const float2* __restrict__ rtab)
{
  __shared__ __align__(16) char lds_raw[36864];
  const int z = blockIdx.z;
  const unsigned short* A = z == 0 ? Xq : z == 1 ? Xk : Xv;
  const unsigned short* W = z == 0 ? Wqb : z == 1 ? Wkb : Wvb;
  const float* bias = z == 0 ? bq : z == 1 ? bk : bv;
  unsigned short* outB = z == 0 ? Qg : z == 1 ? Kg : Vtb;

  const int tid = threadIdx.x, lane = tid & 63, wid = tid >> 6;
  const int wr = wid >> 1, wc = wid & 1;
  const int m0 = blockIdx.x * 128, n0 = blockIdx.y * 128;

  f32x4 acc[4][4];
#pragma unroll
  for (int i = 0; i < 4; i++)
#pragma unroll
    for (int j = 0; j < 4; j++)
#pragma unroll
      for (int r = 0; r < 4; r++) acc[i][j][r] = 0.0f;

  gemm_core128(A, W, m0, n0, lds_raw, acc, lane, wid, wr, wc);
  __syncthreads();

  if (z == 2){ // V transpose via LDS -> Vt[32][64][2048]
    unsigned short* Tb = (unsigned short*)lds_raw + wid * 4608;
#pragma unroll
    for (int i = 0; i < 4; i++)
#pragma unroll
      for (int j = 0; j < 4; j++){
        int n = n0 + wc * 64 + j * 16 + (lane & 15);
        float b = bias[n];
#pragma unroll
        for (int r = 0; r < 4; r++){
          int il = i * 16 + (lane >> 4) * 4 + r;
          Tb[il * 72 + j * 16 + (lane & 15)] = f2bf(gelu_exact(acc[i][j][r] + b));
        }
      }
    __syncthreads();
    int mbase = m0 + wr * 64;
    int hh = (n0 + wc * 64) >> 6;
    int t = lane;
    int i0 = ((mbase >> 11) << 10) + ((mbase & 2047) >> 1);
#pragma unroll
    for (int p = 0; p < 2; p++){
      unsigned short* dst = outB + ((size_t)((hh + (p << 4)) * 64 + t)) * 2048 + i0;
#pragma unroll
      for (int g = 0; g < 8; g++){
        ushort4 pk;
        pk.x = Tb[(p + (g * 4 + 0) * 2) * 72 + t];
        pk.y = Tb[(p + (g * 4 + 1) * 2) * 72 + t];
        pk.z = Tb[(p + (g * 4 + 2) * 2) * 72 + t];
        pk.w = Tb[(p + (g * 4 + 3) * 2) * 72 + t];
        *(ushort4*)(dst + g * 4) = pk;
      }
    }
  } else { // rope + scatter
    float scale = (z == 0) ? QSCALE : 1.0f;
#pragma unroll
    for (int i = 0; i < 4; i++)
#pragma unroll
      for (int j = 0; j < 4; j++){
        int n = n0 + wc * 64 + j * 16 + (lane & 15);
        float b = bias[n];
#pragma unroll
        for (int r = 0; r < 4; r++){
          int m = m0 + wr * 64 + i * 16 + (lane >> 4) * 4 + r;
          float val = gelu_exact(acc[i][j][r] + b);
          float pv = __shfl_xor(val, 1);
          int st = m & 2047;
          float2 cs = rtab[st * 32 + ((n >> 1) & 31)];
          float out = ((n & 1) == 0) ? (val * cs.x - pv * cs.y) : (val * cs.x + pv * cs.y);
          out *= scale;
          int nh = ((n >> 6) & 15) + ((st & 1) << 4);
          int ii = ((m >> 11) << 10) + (st >> 1);
          outB[(nh * 2048 + ii) * 64 + (n & 63)] = f2bf(out);
        }
      }
  }
}

// ---------------- final GEMM: d_out = gelu(aOg @ Wo^T + bo), fp32 out ----------------
// A in GROUP layout aOg[32 n][2048 iq][64 d]; head index == kt (BK=64) -> gather in staging.
__global__ __launch_bounds__(256, 4)
void gemm_o(const unsigned short* __restrict__ aOg, const unsigned short* __restrict__ W,
            const float* __restrict__ bias, float* __restrict__ outF)
{
  __shared__ __align__(16) char lds_raw[32768];
  const int tid = threadIdx.x, lane = tid & 63, wid = tid >> 6;
  const int wr = wid >> 1, wc = wid & 1;
  const int m0 = blockIdx.x * 128, n0 = blockIdx.y * 128;

  f32x4 acc[4][4];
#pragma unroll
  for (int i = 0; i < 4; i++)
#pragma unroll
    for (int j = 0; j < 4; j++)
#pragma unroll
      for (int r = 0; r < 4; r++) acc[i][j][r] = 0.0f;

  const int srow = wid * 8 + (lane >> 3);
  const int scc  = ((lane & 7) ^ (lane >> 3)) * 8;
  const int rxor = lane & 7;

  for (int kt = 0; kt < 16; ++kt){
    int kk = kt * 64;
    __syncthreads();
#pragma unroll
    for (int t = 0; t < 4; t++){
      int row = m0 + t * 32 + srow;
      int nn = kt + ((row & 1) << 4);
      int iq = ((row >> 11) << 10) + ((row & 2047) >> 1);
      gl_lds16(aOg + ((size_t)nn * 2048 + iq) * 64 + scc,
               lds_raw + (t * 2048 + wid * 512) * 2);
      gl_lds16(W + (size_t)(n0 + t * 32 + srow) * 1024 + kk + scc,
               lds_raw + 16384 + (t * 2048 + wid * 512) * 2);
    }
    __syncthreads();
    const unsigned short* Als = (const unsigned short*)lds_raw;
    const unsigned short* Bls = Als + 8192;
#pragma unroll
    for (int dk = 0; dk < 2; ++dk){
      short8 af[4], bfr[4];
      int cidx = (((dk * 4 + (lane >> 4)) ^ rxor) << 3);
#pragma unroll
      for (int i = 0; i < 4; i++){
        af[i]  = *(const short8*)(Als + (wr * 64 + i * 16 + (lane & 15)) * 64 + cidx);
        bfr[i] = *(const short8*)(Bls + (wc * 64 + i * 16 + (lane & 15)) * 64 + cidx);
      }
#pragma unroll
      for (int i = 0; i < 4; i++)
#pragma unroll
        for (int j = 0; j < 4; j++)
          acc[i][j] = __builtin_amdgcn_mfma_f32_16x16x32_bf16(af[i], bfr[j], acc[i][j], 0, 0, 0);
    }
  }
#pragma unroll
  for (int i = 0; i < 4; i++)
#pragma unroll
    for (int j = 0; j < 4; j++){
      int n = n0 + wc * 64 + j * 16 + (lane & 15);
      float b = bias[n];
#pragma unroll
      for (int r = 0; r < 4; r++){
        int m = m0 + wr * 64 + i * 16 + (lane >> 4) * 4 + r;
        outF[m * 1024 + n] = gelu_exact(acc[i][j][r] + b);
      }
    }
}

// ---------------- flash attention: KVBLK=128, fixed-ref softmax, group-layout out ----------------
// Qg/Kg [32][2048][64] bf16 (Q pre-scaled by log2e/32), Vt [32][64][2048] bf16.
// 4 waves x 32 q, 16 KV-tiles of 128 keys: half the barriers/staging-overhead of KVBLK=64.
__global__ __launch_bounds__(256, 2)
void attn_kernel(const unsigned short* __restrict__ Qg,
                 const unsigned short* __restrict__ Kg,
                 const unsigned short* __restrict__ Vt,
                 unsigned short* __restrict__ aOg)
{
  __shared__ __align__(16) char lds_raw[32768];
  unsigned short* Kls = (unsigned short*)lds_raw;            // [128 key][64 d] swz
  unsigned short* Vls = (unsigned short*)(lds_raw + 16384);  // [64 d][128 key] swz
  const int tid = threadIdx.x, lane = tid & 63, wid = tid >> 6;
  const int q31 = lane & 31, h = lane >> 5;
  const int bid = blockIdx.x;
  const int n = (bid & 7) * 4 + ((bid >> 3) >> 4);   // 4 groups per XCD -> KV fits L2
  const int qtile = (bid >> 3) & 15;
  const int qbase = qtile * 128;
  const unsigned short* Qn = Qg + (size_t)n * 2048 * 64;
  const unsigned short* Kn = Kg + (size_t)n * 2048 * 64;
  const unsigned short* Vn = Vt + (size_t)n * 64 * 2048;

  short8 qf[4];
  {
    int qrow = qbase + wid * 32 + q31;
#pragma unroll
    for (int c = 0; c < 4; c++)
      qf[c] = *(const short8*)(Qn + qrow * 64 + c * 16 + h * 8);
  }
  f32x16 o0, o1, lsum;
#pragma unroll
  for (int r = 0; r < 16; r++){ o0[r] = 0.0f; o1[r] = 0.0f; lsum[r] = 0.0f; }

  short8 rk[4], rv[4];
#pragma unroll
  for (int t = 0; t < 4; t++){
    int chunk = t * 256 + tid;
    rk[t] = *(const short8*)(Kn + (chunk >> 3) * 64 + (chunk & 7) * 8);
    rv[t] = *(const short8*)(Vn + (size_t)(chunk >> 4) * 2048 + (chunk & 15) * 8);
  }

  for (int kb = 0; kb < 2048; kb += 128){
    __syncthreads();
#pragma unroll
    for (int t = 0; t < 4; t++){
      int chunk = t * 256 + tid;
      { int row = chunk >> 3, c = chunk & 7;
        *(short8*)(Kls + row * 64 + ((c ^ (row & 7)) << 3)) = rk[t]; }
      { int row = chunk >> 4, c = chunk & 15;
        *(short8*)(Vls + row * 128 + ((c ^ (row & 7)) << 3)) = rv[t]; }
    }
    __syncthreads();
    if (kb + 128 < 2048){
#pragma unroll
      for (int t = 0; t < 4; t++){
        int chunk = t * 256 + tid;
        rk[t] = *(const short8*)(Kn + (kb + 128 + (chunk >> 3)) * 64 + (chunk & 7) * 8);
        rv[t] = *(const short8*)(Vn + (size_t)(chunk >> 4) * 2048 + kb + 128 + (chunk & 15) * 8);
      }
    }
    // S^T = K * Q : 4 key-groups of 32
    f32x16 s[4];
#pragma unroll
    for (int g = 0; g < 4; g++)
#pragma unroll
      for (int r = 0; r < 16; r++) s[g][r] = 0.0f;
    __builtin_amdgcn_s_setprio(1);
#pragma unroll
    for (int c = 0; c < 4; c++){
      int sl = (c << 1) | h;
#pragma unroll
      for (int g = 0; g < 4; g++){
        int row = g * 32 + q31;
        short8 kf = *(const short8*)(Kls + row * 64 + ((sl ^ (row & 7)) << 3));
        s[g] = __builtin_amdgcn_mfma_f32_32x32x16_bf16(kf, qf[c], s[g], 0, 0, 0);
      }
    }
    __builtin_amdgcn_s_setprio(0);
    // P = exp2(S), fixed reference 0; l accumulates vector-wise
#pragma unroll
    for (int g = 0; g < 4; g++){
#pragma unroll
      for (int r = 0; r < 16; r++) s[g][r] = exp2_fast(s[g][r]);
      lsum += s[g];
    }
    // pack P -> bf16 B-frags; PV: O^T += V^T * P^T  (8 key-chunks of 16)
    __builtin_amdgcn_s_setprio(1);
#pragma unroll
    for (int kc = 0; kc < 8; kc++){
      const f32x16& S = s[kc >> 1];
      const int rb = (kc & 1) * 8;
      unsigned a0, a1, b0, b1;
      asm("v_cvt_pk_bf16_f32 %0, %1, %2" : "=v"(a0) : "v"(S[rb + 0]), "v"(S[rb + 1]));
      asm("v_cvt_pk_bf16_f32 %0, %1, %2" : "=v"(a1) : "v"(S[rb + 2]), "v"(S[rb + 3]));
      asm("v_cvt_pk_bf16_f32 %0, %1, %2" : "=v"(b0) : "v"(S[rb + 4]), "v"(S[rb + 5]));
      asm("v_cvt_pk_bf16_f32 %0, %1, %2" : "=v"(b1) : "v"(S[rb + 6]), "v"(S[rb + 7]));
      asm("v_permlane32_swap_b32 %0, %1" : "+v"(a0), "+v"(b0));
      asm("v_permlane32_swap_b32 %0, %1" : "+v"(a1), "+v"(b1));
      union { int i[4]; short8 s; } u;
      u.i[0] = (int)a0; u.i[1] = (int)a1; u.i[2] = (int)b0; u.i[3] = (int)b1;
      short8 pf = u.s;
      int sl = (kc << 1) | h;
      {
        short8 vf = *(const short8*)(Vls + q31 * 128 + ((sl ^ (q31 & 7)) << 3));
        o0 = __builtin_amdgcn_mfma_f32_32x32x16_bf16(vf, pf, o0, 0, 0, 0);
      }
      {
        int dr = 32 + q31;
        short8 vf = *(const short8*)(Vls + dr * 128 + ((sl ^ (dr & 7)) << 3));
        o1 = __builtin_amdgcn_mfma_f32_32x32x16_bf16(vf, pf, o1, 0, 0, 0);
      }
    }
    __builtin_amdgcn_s_setprio(0);
  }
  // final l: reduce lsum vector, combine the two key-half lanes
  float l = 0.0f;
#pragma unroll
  for (int r = 0; r < 16; r++) l += lsum[r];
  l += __shfl_xor(l, 32);
  // epilogue: O^T -> aOg[n][iq][d]
  float rl = 1.0f / l;
  const int iq = qbase + wid * 32 + q31;
  unsigned short* dst = aOg + ((size_t)n * 2048 + iq) * 64;
#pragma unroll
  for (int r = 0; r < 16; r++){
    int dl = (r & 3) + 8 * (r >> 2) + 4 * h;
    dst[dl]      = f2bf(o0[r] * rl);
    dst[32 + dl] = f2bf(o1[r] * rl);
  }
}

// ---------------- launch ----------------
extern "C" void kernel_launch(void* const* d_in, const int* in_sizes, int n_in,
                              void* d_out, int out_size, void* d_ws, size_t ws_size,
                              hipStream_t stream)
{
  const float* q  = (const float*)d_in[0];
  const float* k  = (const float*)d_in[1];
  const float* v  = (const float*)d_in[2];
  const float* Wq = (const float*)d_in[3];
  const float* bq = (const float*)d_in[4];
  const float* Wk = (const float*)d_in[5];
  const float* bk = (const float*)d_in[6];
  const float* Wv = (const float*)d_in[7];
  const float* bv = (const float*)d_in[8];
  const float* Wo = (const float*)d_in[9];
  const float* bo = (const float*)d_in[10];

  char* ws = (char*)d_ws;
  size_t off = 0;
  auto alloc = [&](size_t bytes) -> void* {
    void* p = ws + off;
    off += (bytes + 255) & ~(size_t)255;
    return p;
  };
  unsigned short* Xq  = (unsigned short*)alloc(4194304ull * 2);
  unsigned short* Xk  = (unsigned short*)alloc(4194304ull * 2);
  unsigned short* Xv  = (unsigned short*)alloc(4194304ull * 2);
  unsigned short* Wqb = (unsigned short*)alloc(1048576ull * 2);
  unsigned short* Wkb = (unsigned short*)alloc(1048576ull * 2);
  unsigned short* Wvb = (unsigned short*)alloc(1048576ull * 2);
  unsigned short* Wob = (unsigned short*)alloc(1048576ull * 2);
  unsigned short* Qg  = (unsigned short*)alloc(4194304ull * 2);
  unsigned short* Kg  = (unsigned short*)alloc(4194304ull * 2);
  unsigned short* Vtb = (unsigned short*)alloc(4194304ull * 2);
  unsigned short* aOg = (unsigned short*)alloc(4194304ull * 2);
  float2*         rtab = (float2*)alloc(2048ull * 32 * 8);

  ConvArgs ca;
  const float* srcs[7] = {q, k, v, Wq, Wk, Wv, Wo};
  unsigned short* dsts[7] = {Xq, Xk, Xv, Wqb, Wkb, Wvb, Wob};
  int ns[7] = {4194304, 4194304, 4194304, 1048576, 1048576, 1048576, 1048576};
  for (int i = 0; i < 7; i++){ ca.src[i] = srcs[i]; ca.dst[i] = dsts[i]; ca.n[i] = ns[i]; }

  conv_kernel<<<dim3(4096, 7), 256, 0, stream>>>(ca);
  rope_kernel<<<dim3(256), 256, 0, stream>>>(rtab);
  gemm_qkv<<<dim3(32, 8, 3), 256, 0, stream>>>(Xq, Xk, Xv, Wqb, Wkb, Wvb, bq, bk, bv, Qg, Kg, Vtb, rtab);
  attn_kernel<<<dim3(512), 256, 0, stream>>>(Qg, Kg, Vtb, aOg);
  gemm_o<<<dim3(32, 8), 256, 0, stream>>>(aOg, Wob, bo, (float*)d_out);
}